// Round 1
// baseline (2242.408 us; speedup 1.0000x reference)
//
#include <hip/hip_runtime.h>
#include <stdint.h>

#define DEVI __device__ __forceinline__

typedef __bf16 bf16x8 __attribute__((ext_vector_type(8)));
typedef float floatx4 __attribute__((ext_vector_type(4)));

// ---------- helpers ----------
DEVI uint16_t f2bf(float f) {
  union { float f; uint32_t u; } c; c.f = f;
  uint32_t u = c.u;
  return (uint16_t)((u + 0x7fffu + ((u >> 16) & 1u)) >> 16);  // RNE
}
DEVI float bf2f(uint16_t h) {
  union { uint32_t u; float f; } c; c.u = ((uint32_t)h) << 16;
  return c.f;
}
DEVI void load_lds_16(const void* g, void* l) {
  __builtin_amdgcn_global_load_lds(
      (const __attribute__((address_space(1))) void*)g,
      (__attribute__((address_space(3))) void*)l, 16, 0, 0);
}
DEVI float sigm(float x) { return 1.f / (1.f + __expf(-x)); }
DEVI float tanh_s(float x) {
  float xc = fminf(fmaxf(x, -15.f), 15.f);
  float e = __expf(2.f * xc);
  return (e - 1.f) / (e + 1.f);
}

// ---------- workspace layout (bytes) ----------
// emb_bf [50000][256] bf16 ; wxt [2048][4096] bf16 (n = h*4+gate, k = p*256+i)
// wht [2048][512] bf16     ; bias [2048] f32
// pre [T=256][B=64][2048] bf16 ; h0,c,h1 [64][512] f32
static constexpr size_t OFF_EMB  = 0;
static constexpr size_t OFF_WXT  = 25600000;
static constexpr size_t OFF_WHT  = OFF_WXT + 16777216;
static constexpr size_t OFF_BIAS = OFF_WHT + 2097152;
static constexpr size_t OFF_PRE  = OFF_BIAS + 8192;
static constexpr size_t OFF_H0   = OFF_PRE + 67108864;
static constexpr size_t OFF_C    = OFF_H0 + 131072;
static constexpr size_t OFF_H1   = OFF_C + 131072;

// ---------- 1. embedding -> bf16, row 0 zeroed ----------
__global__ __launch_bounds__(256) void k_emb_cvt(const float* __restrict__ emb,
                                                 uint16_t* __restrict__ dst) {
  size_t tid = (size_t)blockIdx.x * 256 + threadIdx.x;
  size_t e = tid * 8;                       // 8 elems / thread
  int v = (int)(e >> 8);
  const float4* s = (const float4*)(emb + e);
  float4 f0 = s[0], f1 = s[1];
  if (v == 0) { f0 = make_float4(0.f, 0.f, 0.f, 0.f); f1 = f0; }
  uint32_t w0 = f2bf(f0.x) | ((uint32_t)f2bf(f0.y) << 16);
  uint32_t w1 = f2bf(f0.z) | ((uint32_t)f2bf(f0.w) << 16);
  uint32_t w2 = f2bf(f1.x) | ((uint32_t)f2bf(f1.y) << 16);
  uint32_t w3 = f2bf(f1.z) | ((uint32_t)f2bf(f1.w) << 16);
  *(uint4*)(dst + e) = make_uint4(w0, w1, w2, w3);
}

// ---------- 2. weight transpose+convert: W_g[K][512] (g=f,i,g,o) -> dst[n=h*4+g][K] bf16 ----------
__global__ __launch_bounds__(256) void k_wt(const float* __restrict__ w0, const float* __restrict__ w1,
                                            const float* __restrict__ w2, const float* __restrict__ w3,
                                            int K, uint16_t* __restrict__ dst) {
  __shared__ float tile[64 * 64];           // [n_local 64][k_local 64]
  int k0 = blockIdx.x * 64;
  int n0 = blockIdx.y * 64;
  int h0 = blockIdx.y * 16;
  int g = threadIdx.x >> 6, di = threadIdx.x & 63;
  const float* w = (g == 0) ? w0 : (g == 1) ? w1 : (g == 2) ? w2 : w3;
  const float4* src = (const float4*)(w + (size_t)(k0 + di) * 512 + h0);
  float4 a = src[0], b = src[1], c = src[2], d = src[3];
  float vals[16] = {a.x, a.y, a.z, a.w, b.x, b.y, b.z, b.w,
                    c.x, c.y, c.z, c.w, d.x, d.y, d.z, d.w};
#pragma unroll
  for (int dh = 0; dh < 16; ++dh) tile[(dh * 4 + g) * 64 + di] = vals[dh];
  __syncthreads();
  int nl = threadIdx.x >> 2, ch = threadIdx.x & 3;
  uint32_t wb[8];
#pragma unroll
  for (int j = 0; j < 8; ++j) {
    float lo = tile[nl * 64 + ch * 16 + j * 2];
    float hi = tile[nl * 64 + ch * 16 + j * 2 + 1];
    wb[j] = f2bf(lo) | ((uint32_t)f2bf(hi) << 16);
  }
  uint4* dp = (uint4*)(dst + (size_t)(n0 + nl) * K + k0 + ch * 16);
  dp[0] = make_uint4(wb[0], wb[1], wb[2], wb[3]);
  dp[1] = make_uint4(wb[4], wb[5], wb[6], wb[7]);
}

// ---------- 3. bias pack: bias[n=h*4+g] ----------
__global__ __launch_bounds__(256) void k_bias(const float* __restrict__ b0, const float* __restrict__ b1,
                                              const float* __restrict__ b2, const float* __restrict__ b3,
                                              float* __restrict__ dst) {
  int n = blockIdx.x * 256 + threadIdx.x;
  int h = n >> 2, g = n & 3;
  const float* b = (g == 0) ? b0 : (g == 1) ? b1 : (g == 2) ? b2 : b3;
  dst[n] = b[h];
}

// ---------- 4. gather-GEMM: pre[m=t*64+b][n] = sum_k emb_bf[x[b,p,t]][i] * wxt[n][k] ----------
__global__ __launch_bounds__(256) void k_gemm(const uint16_t* __restrict__ embbf,
                                              const int* __restrict__ x,
                                              const uint16_t* __restrict__ wxt,
                                              uint16_t* __restrict__ pre) {
  __shared__ uint16_t As[128 * 64];
  __shared__ uint16_t Bs[128 * 64];
  const int tid = threadIdx.x;
  const int wv = tid >> 6, ln = tid & 63;
  const int wm = wv >> 1, wn = wv & 1;
  const int M0 = blockIdx.x * 128, N0 = blockIdx.y * 128;
  const int srow = ln >> 3, schunk = ln & 7;

  const int* xrow[4];
  const uint16_t* bbase[4];
  uint16_t* ldsA[4];
  uint16_t* ldsB[4];
#pragma unroll
  for (int j = 0; j < 4; ++j) {
    int r = j * 32 + wv * 8 + srow;
    int m = M0 + r;
    int t = m >> 6, b = m & 63;
    xrow[j] = x + b * 4096 + t;                              // x[b][p][t], + p*256
    bbase[j] = wxt + (size_t)(N0 + r) * 4096 + schunk * 8;
    ldsA[j] = As + (j * 32 + wv * 8) * 64;
    ldsB[j] = Bs + (j * 32 + wv * 8) * 64;
  }

  const int q = ln >> 4, l16 = ln & 15;
  int aoff[4], boff[4];
#pragma unroll
  for (int mt = 0; mt < 4; ++mt) aoff[mt] = (wm * 64 + mt * 16 + l16) * 64 + q * 8;
#pragma unroll
  for (int nt = 0; nt < 4; ++nt) boff[nt] = (wn * 64 + nt * 16 + l16) * 64 + q * 8;

  floatx4 acc[4][4] = {};

  for (int p = 0; p < 16; ++p) {
    const uint16_t* abase[4];
#pragma unroll
    for (int j = 0; j < 4; ++j) {
      int idx = xrow[j][p << 8];
      abase[j] = embbf + (size_t)idx * 256 + schunk * 8;
    }
#pragma unroll 1
    for (int ki = 0; ki < 4; ++ki) {
      __syncthreads();
#pragma unroll
      for (int j = 0; j < 4; ++j) load_lds_16(abase[j] + ki * 64, ldsA[j]);
#pragma unroll
      for (int j = 0; j < 4; ++j) load_lds_16(bbase[j] + p * 256 + ki * 64, ldsB[j]);
      __syncthreads();
#pragma unroll
      for (int kk = 0; kk < 2; ++kk) {
        bf16x8 a[4];
#pragma unroll
        for (int mt = 0; mt < 4; ++mt) a[mt] = *(const bf16x8*)(As + aoff[mt] + kk * 32);
#pragma unroll
        for (int nt = 0; nt < 4; ++nt) {
          bf16x8 bv = *(const bf16x8*)(Bs + boff[nt] + kk * 32);
#pragma unroll
          for (int mt = 0; mt < 4; ++mt)
            acc[mt][nt] = __builtin_amdgcn_mfma_f32_16x16x32_bf16(a[mt], bv, acc[mt][nt], 0, 0, 0);
        }
      }
    }
  }

#pragma unroll
  for (int mt = 0; mt < 4; ++mt) {
    int mg = M0 + wm * 64 + mt * 16 + q * 4;
#pragma unroll
    for (int nt = 0; nt < 4; ++nt) {
      int ng = N0 + wn * 64 + nt * 16 + l16;
#pragma unroll
      for (int r = 0; r < 4; ++r)
        pre[(size_t)(mg + r) * 2048 + ng] = f2bf(acc[mt][nt][r]);
    }
  }
}

// ---------- 5. one LSTM step: 64 WGs = 4 batch-groups(16) x 16 col-strips(128 n = 32 h x 4 gates) ----------
__global__ __launch_bounds__(256) void k_step(const float* __restrict__ hin,
                                              float* __restrict__ hout,
                                              float* __restrict__ c,
                                              const uint16_t* __restrict__ pre_t,
                                              const uint16_t* __restrict__ wht,
                                              const float* __restrict__ bias) {
  __shared__ uint16_t Ahs[16 * 520];        // h tile bf16, padded stride 520
  __shared__ uint16_t Bs[128 * 64];
  __shared__ uint16_t pres[16 * 128];
  __shared__ float gates[16 * 128];

  const int tid = threadIdx.x;
  const int wv = tid >> 6, ln = tid & 63;
  const int bg = blockIdx.x >> 4, cg = blockIdx.x & 15;
  const int N0 = cg * 128;

  {  // stage pre strip [16][128] bf16
    int row = tid >> 4, ch = tid & 15;
    uint4 v = *(const uint4*)(pre_t + (size_t)(bg * 16 + row) * 2048 + N0 + ch * 8);
    *(uint4*)(pres + row * 128 + ch * 8) = v;
  }
  {  // stage A = h[bg*16 .. +16][512] -> bf16 LDS
    int row = tid >> 4, seg = tid & 15;
    const float4* s = (const float4*)(hin + (size_t)(bg * 16 + row) * 512 + seg * 32);
#pragma unroll
    for (int j = 0; j < 8; j += 2) {
      float4 f0 = s[j], f1 = s[j + 1];
      uint32_t w0 = f2bf(f0.x) | ((uint32_t)f2bf(f0.y) << 16);
      uint32_t w1 = f2bf(f0.z) | ((uint32_t)f2bf(f0.w) << 16);
      uint32_t w2 = f2bf(f1.x) | ((uint32_t)f2bf(f1.y) << 16);
      uint32_t w3 = f2bf(f1.z) | ((uint32_t)f2bf(f1.w) << 16);
      *(uint4*)(Ahs + row * 520 + seg * 32 + j * 4) = make_uint4(w0, w1, w2, w3);
    }
  }

  const int srow = ln >> 3, schunk = ln & 7;
  const uint16_t* bbase[4];
  uint16_t* ldsB[4];
#pragma unroll
  for (int j = 0; j < 4; ++j) {
    int r = j * 32 + wv * 8 + srow;
    bbase[j] = wht + (size_t)(N0 + r) * 512 + schunk * 8;
    ldsB[j] = Bs + (j * 32 + wv * 8) * 64;
  }
  const int q = ln >> 4, l16 = ln & 15;
  floatx4 acc[2] = {};
  const int aoffbase = l16 * 520 + q * 8;
  int boff[2];
  boff[0] = (wv * 32 + l16) * 64 + q * 8;
  boff[1] = (wv * 32 + 16 + l16) * 64 + q * 8;

#pragma unroll 1
  for (int kc = 0; kc < 8; ++kc) {
    __syncthreads();
#pragma unroll
    for (int j = 0; j < 4; ++j) load_lds_16(bbase[j] + kc * 64, ldsB[j]);
    __syncthreads();
#pragma unroll
    for (int kk = 0; kk < 2; ++kk) {
      bf16x8 a = *(const bf16x8*)(Ahs + aoffbase + kc * 64 + kk * 32);
#pragma unroll
      for (int nt = 0; nt < 2; ++nt) {
        bf16x8 bv = *(const bf16x8*)(Bs + boff[nt] + kk * 32);
        acc[nt] = __builtin_amdgcn_mfma_f32_16x16x32_bf16(a, bv, acc[nt], 0, 0, 0);
      }
    }
  }

#pragma unroll
  for (int nt = 0; nt < 2; ++nt) {
    int n_l = wv * 32 + nt * 16 + l16;
    float bs = bias[N0 + n_l];
#pragma unroll
    for (int r = 0; r < 4; ++r) {
      int row = q * 4 + r;
      gates[row * 128 + n_l] = acc[nt][r] + bs + bf2f(pres[row * 128 + n_l]);
    }
  }
  __syncthreads();

#pragma unroll
  for (int it = 0; it < 2; ++it) {
    int item = tid * 2 + it;
    int b_l = item >> 5, h_l = item & 31;
    float4 v = *(const float4*)(gates + b_l * 128 + h_l * 4);
    float fg = sigm(v.x), ig = sigm(v.y), gg = tanh_s(v.z), og = sigm(v.w);
    size_t idx = (size_t)(bg * 16 + b_l) * 512 + cg * 32 + h_l;
    float cn = fg * c[idx] + ig * gg;
    c[idx] = cn;
    hout[idx] = og * tanh_s(cn);
  }
}

// ---------- 6. final: out = h @ W_lin + b_lin; copy h, c ----------
__global__ __launch_bounds__(256) void k_final(const float* __restrict__ h, const float* __restrict__ c,
                                               const float* __restrict__ wl, const float* __restrict__ bl,
                                               float* __restrict__ out) {
  __shared__ float red[256];
  int b = blockIdx.x, t = threadIdx.x;
  const float* hb = h + (size_t)b * 512;
  if (t < 128) {
    ((float4*)(out + 320 + (size_t)b * 512))[t] = ((const float4*)hb)[t];
    ((float4*)(out + 320 + 32768 + (size_t)b * 512))[t] = ((const float4*)(c + (size_t)b * 512))[t];
  }
  float h0 = hb[t], h1 = hb[t + 256];
  for (int o = 0; o < 5; ++o) {
    red[t] = h0 * wl[t * 5 + o] + h1 * wl[(t + 256) * 5 + o];
    __syncthreads();
    for (int s = 128; s > 0; s >>= 1) {
      if (t < s) red[t] += red[t + s];
      __syncthreads();
    }
    if (t == 0) out[b * 5 + o] = red[0] + bl[o];
    __syncthreads();
  }
}

// ---------- launch ----------
extern "C" void kernel_launch(void* const* d_in, const int* in_sizes, int n_in,
                              void* d_out, int out_size, void* d_ws, size_t ws_size,
                              hipStream_t stream) {
  const int*   x   = (const int*)d_in[0];
  const float* emb = (const float*)d_in[1];
  const float* wfx = (const float*)d_in[2];
  const float* wfh = (const float*)d_in[3];
  const float* bf_ = (const float*)d_in[4];
  const float* wix = (const float*)d_in[5];
  const float* wih = (const float*)d_in[6];
  const float* bi_ = (const float*)d_in[7];
  const float* wgx = (const float*)d_in[8];
  const float* wgh = (const float*)d_in[9];
  const float* bg_ = (const float*)d_in[10];
  const float* wox = (const float*)d_in[11];
  const float* woh = (const float*)d_in[12];
  const float* bo_ = (const float*)d_in[13];
  const float* wl  = (const float*)d_in[14];
  const float* bl  = (const float*)d_in[15];
  float* out = (float*)d_out;
  char* ws = (char*)d_ws;

  uint16_t* embbf = (uint16_t*)(ws + OFF_EMB);
  uint16_t* wxt   = (uint16_t*)(ws + OFF_WXT);
  uint16_t* wht   = (uint16_t*)(ws + OFF_WHT);
  float*    bias  = (float*)(ws + OFF_BIAS);
  uint16_t* pre   = (uint16_t*)(ws + OFF_PRE);
  float*    h0b   = (float*)(ws + OFF_H0);
  float*    cb    = (float*)(ws + OFF_C);
  float*    h1b   = (float*)(ws + OFF_H1);

  hipMemsetAsync(ws + OFF_H0, 0, 262144, stream);  // zero h0 + c

  hipLaunchKernelGGL(k_emb_cvt, dim3(6250), dim3(256), 0, stream, emb, embbf);
  hipLaunchKernelGGL(k_wt, dim3(64, 32), dim3(256), 0, stream, wfx, wix, wgx, wox, 4096, wxt);
  hipLaunchKernelGGL(k_wt, dim3(8, 32), dim3(256), 0, stream, wfh, wih, wgh, woh, 512, wht);
  hipLaunchKernelGGL(k_bias, dim3(8), dim3(256), 0, stream, bf_, bi_, bg_, bo_, bias);
  hipLaunchKernelGGL(k_gemm, dim3(128, 16), dim3(256), 0, stream, embbf, x, wxt, pre);

  for (int t = 0; t < 256; ++t) {
    const float* hi = (t & 1) ? h1b : h0b;
    float*       ho = (t & 1) ? h0b : h1b;
    hipLaunchKernelGGL(k_step, dim3(64), dim3(256), 0, stream, hi, ho, cb,
                       pre + (size_t)t * 64 * 2048, wht, bias);
  }
  hipLaunchKernelGGL(k_final, dim3(64), dim3(256), 0, stream, h0b, cb, wl, bl, out);
}

// Round 2
// 1179.630 us; speedup vs baseline: 1.9009x; 1.9009x over previous
//
#include <hip/hip_runtime.h>
#include <stdint.h>

#define DEVI __device__ __forceinline__

typedef __bf16 bf16x8 __attribute__((ext_vector_type(8)));
typedef float floatx4 __attribute__((ext_vector_type(4)));

// ---------- helpers ----------
DEVI uint16_t f2bf(float f) {
  union { float f; uint32_t u; } c; c.f = f;
  uint32_t u = c.u;
  return (uint16_t)((u + 0x7fffu + ((u >> 16) & 1u)) >> 16);  // RNE
}
DEVI float bf2f(uint16_t h) {
  union { uint32_t u; float f; } c; c.u = ((uint32_t)h) << 16;
  return c.f;
}
DEVI void load_lds_16(const void* g, void* l) {
  __builtin_amdgcn_global_load_lds(
      (const __attribute__((address_space(1))) void*)g,
      (__attribute__((address_space(3))) void*)l, 16, 0, 0);
}
DEVI float sigm(float x) { return 1.f / (1.f + __expf(-x)); }
DEVI float tanh_s(float x) {
  float xc = fminf(fmaxf(x, -15.f), 15.f);
  float e = __expf(2.f * xc);
  return (e - 1.f) / (e + 1.f);
}

// ---------- workspace layout (bytes) ----------
// emb_bf [50000][256] bf16 at 0; ALIASED by hbufs[256][64][512] bf16 (written
// only during k_rec, after k_gemm's last emb read; k_rec dispatch boundary
// invalidates stale L2 lines).
static constexpr size_t OFF_EMB   = 0;
static constexpr size_t OFF_HBUF  = 0;                        // 256*65536 = 16.78MB
static constexpr size_t OFF_WXT   = 25600000;                 // [2048][4096] bf16
static constexpr size_t OFF_WHT   = OFF_WXT + 16777216;       // [2048][512] bf16
static constexpr size_t OFF_BIAS  = OFF_WHT + 2097152;        // [2048] f32
static constexpr size_t OFF_PRE   = OFF_BIAS + 8192;          // [256][64][2048] bf16
static constexpr size_t OFF_FLAGS = OFF_PRE + 67108864;       // 64 int (poison=negative)
static constexpr size_t OFF_HF    = OFF_FLAGS + 4096;         // h_t f32 [64][512]
static constexpr size_t OFF_CF    = OFF_HF + 131072;          // c_t f32 [64][512]

// ---------- 1. embedding -> bf16, row 0 zeroed ----------
__global__ __launch_bounds__(256) void k_emb_cvt(const float* __restrict__ emb,
                                                 uint16_t* __restrict__ dst) {
  size_t tid = (size_t)blockIdx.x * 256 + threadIdx.x;
  size_t e = tid * 8;
  int v = (int)(e >> 8);
  const float4* s = (const float4*)(emb + e);
  float4 f0 = s[0], f1 = s[1];
  if (v == 0) { f0 = make_float4(0.f, 0.f, 0.f, 0.f); f1 = f0; }
  uint32_t w0 = f2bf(f0.x) | ((uint32_t)f2bf(f0.y) << 16);
  uint32_t w1 = f2bf(f0.z) | ((uint32_t)f2bf(f0.w) << 16);
  uint32_t w2 = f2bf(f1.x) | ((uint32_t)f2bf(f1.y) << 16);
  uint32_t w3 = f2bf(f1.z) | ((uint32_t)f2bf(f1.w) << 16);
  *(uint4*)(dst + e) = make_uint4(w0, w1, w2, w3);
}

// ---------- 2. weight transpose+convert: W_g[K][512] -> dst[n=h*4+g][K] bf16 ----------
__global__ __launch_bounds__(256) void k_wt(const float* __restrict__ w0, const float* __restrict__ w1,
                                            const float* __restrict__ w2, const float* __restrict__ w3,
                                            int K, uint16_t* __restrict__ dst) {
  __shared__ float tile[64 * 64];
  int k0 = blockIdx.x * 64;
  int n0 = blockIdx.y * 64;
  int h0 = blockIdx.y * 16;
  int g = threadIdx.x >> 6, di = threadIdx.x & 63;
  const float* w = (g == 0) ? w0 : (g == 1) ? w1 : (g == 2) ? w2 : w3;
  const float4* src = (const float4*)(w + (size_t)(k0 + di) * 512 + h0);
  float4 a = src[0], b = src[1], c = src[2], d = src[3];
  float vals[16] = {a.x, a.y, a.z, a.w, b.x, b.y, b.z, b.w,
                    c.x, c.y, c.z, c.w, d.x, d.y, d.z, d.w};
#pragma unroll
  for (int dh = 0; dh < 16; ++dh) tile[(dh * 4 + g) * 64 + di] = vals[dh];
  __syncthreads();
  int nl = threadIdx.x >> 2, ch = threadIdx.x & 3;
  uint32_t wb[8];
#pragma unroll
  for (int j = 0; j < 8; ++j) {
    float lo = tile[nl * 64 + ch * 16 + j * 2];
    float hi = tile[nl * 64 + ch * 16 + j * 2 + 1];
    wb[j] = f2bf(lo) | ((uint32_t)f2bf(hi) << 16);
  }
  uint4* dp = (uint4*)(dst + (size_t)(n0 + nl) * K + k0 + ch * 16);
  dp[0] = make_uint4(wb[0], wb[1], wb[2], wb[3]);
  dp[1] = make_uint4(wb[4], wb[5], wb[6], wb[7]);
}

// ---------- 3. bias pack ----------
__global__ __launch_bounds__(256) void k_bias(const float* __restrict__ b0, const float* __restrict__ b1,
                                              const float* __restrict__ b2, const float* __restrict__ b3,
                                              float* __restrict__ dst) {
  int n = blockIdx.x * 256 + threadIdx.x;
  int h = n >> 2, g = n & 3;
  const float* b = (g == 0) ? b0 : (g == 1) ? b1 : (g == 2) ? b2 : b3;
  dst[n] = b[h];
}

// ---------- 4. gather-GEMM (unchanged, known-good) ----------
__global__ __launch_bounds__(256) void k_gemm(const uint16_t* __restrict__ embbf,
                                              const int* __restrict__ x,
                                              const uint16_t* __restrict__ wxt,
                                              uint16_t* __restrict__ pre) {
  __shared__ uint16_t As[128 * 64];
  __shared__ uint16_t Bs[128 * 64];
  const int tid = threadIdx.x;
  const int wv = tid >> 6, ln = tid & 63;
  const int wm = wv >> 1, wn = wv & 1;
  const int M0 = blockIdx.x * 128, N0 = blockIdx.y * 128;
  const int srow = ln >> 3, schunk = ln & 7;

  const int* xrow[4];
  const uint16_t* bbase[4];
  uint16_t* ldsA[4];
  uint16_t* ldsB[4];
#pragma unroll
  for (int j = 0; j < 4; ++j) {
    int r = j * 32 + wv * 8 + srow;
    int m = M0 + r;
    int t = m >> 6, b = m & 63;
    xrow[j] = x + b * 4096 + t;
    bbase[j] = wxt + (size_t)(N0 + r) * 4096 + schunk * 8;
    ldsA[j] = As + (j * 32 + wv * 8) * 64;
    ldsB[j] = Bs + (j * 32 + wv * 8) * 64;
  }

  const int q = ln >> 4, l16 = ln & 15;
  int aoff[4], boff[4];
#pragma unroll
  for (int mt = 0; mt < 4; ++mt) aoff[mt] = (wm * 64 + mt * 16 + l16) * 64 + q * 8;
#pragma unroll
  for (int nt = 0; nt < 4; ++nt) boff[nt] = (wn * 64 + nt * 16 + l16) * 64 + q * 8;

  floatx4 acc[4][4] = {};

  for (int p = 0; p < 16; ++p) {
    const uint16_t* abase[4];
#pragma unroll
    for (int j = 0; j < 4; ++j) {
      int idx = xrow[j][p << 8];
      abase[j] = embbf + (size_t)idx * 256 + schunk * 8;
    }
#pragma unroll 1
    for (int ki = 0; ki < 4; ++ki) {
      __syncthreads();
#pragma unroll
      for (int j = 0; j < 4; ++j) load_lds_16(abase[j] + ki * 64, ldsA[j]);
#pragma unroll
      for (int j = 0; j < 4; ++j) load_lds_16(bbase[j] + p * 256 + ki * 64, ldsB[j]);
      __syncthreads();
#pragma unroll
      for (int kk = 0; kk < 2; ++kk) {
        bf16x8 a[4];
#pragma unroll
        for (int mt = 0; mt < 4; ++mt) a[mt] = *(const bf16x8*)(As + aoff[mt] + kk * 32);
#pragma unroll
        for (int nt = 0; nt < 4; ++nt) {
          bf16x8 bv = *(const bf16x8*)(Bs + boff[nt] + kk * 32);
#pragma unroll
          for (int mt = 0; mt < 4; ++mt)
            acc[mt][nt] = __builtin_amdgcn_mfma_f32_16x16x32_bf16(a[mt], bv, acc[mt][nt], 0, 0, 0);
        }
      }
    }
  }

#pragma unroll
  for (int mt = 0; mt < 4; ++mt) {
    int mg = M0 + wm * 64 + mt * 16 + q * 4;
#pragma unroll
    for (int nt = 0; nt < 4; ++nt) {
      int ng = N0 + wn * 64 + nt * 16 + l16;
#pragma unroll
      for (int r = 0; r < 4; ++r)
        pre[(size_t)(mg + r) * 2048 + ng] = f2bf(acc[mt][nt][r]);
    }
  }
}

// ---------- 5. persistent recurrence: 64 WGs = 4 bg x 16 cg, 256 steps ----------
// WG (bg,cg): A = h[bg*16..+16][512] bf16, B = wht[cg*128..+128][512] in REGISTERS,
// c slice in registers. h passed through per-step unique global buffers (bf16,
// agent-scope stores -> LLC; readers cold-miss). Per-bg flag barrier (16 flags).
__global__ __launch_bounds__(256) void k_rec(const uint16_t* __restrict__ pre,
                                             const uint16_t* __restrict__ wht,
                                             const float* __restrict__ bias,
                                             uint16_t* __restrict__ hbufs,
                                             int* __restrict__ flags,
                                             float* __restrict__ hfin,
                                             float* __restrict__ cfin) {
  __shared__ uint16_t Ahs[16 * 544];        // 16 rows x 512, row stride 544 (pad 64B)
  __shared__ uint16_t pres[2][16 * 128];    // pre strip double buffer
  __shared__ float gates[16 * 128];

  const int tid = threadIdx.x;
  const int wv = tid >> 6, ln = tid & 63;
  const int q = ln >> 4, l16 = ln & 15;
  const int bg = blockIdx.x >> 4, cg = blockIdx.x & 15;
  const int N0 = cg * 128;

  // B fragments resident in VGPRs: wave wv owns n-cols N0 + wv*32 .. +32
  bf16x8 Bfrag[16][2];
#pragma unroll
  for (int kc = 0; kc < 16; ++kc)
#pragma unroll
    for (int nt = 0; nt < 2; ++nt) {
      int n = N0 + wv * 32 + nt * 16 + l16;
      Bfrag[kc][nt] = *(const bf16x8*)(wht + (size_t)n * 512 + kc * 32 + q * 8);
    }
  float breg[2];
#pragma unroll
  for (int nt = 0; nt < 2; ++nt) breg[nt] = bias[N0 + wv * 32 + nt * 16 + l16];

  float creg[2] = {0.f, 0.f};

  // prefetch pre strip for t=0
  {
    const uint16_t* g = pre + (size_t)(bg * 16 + wv * 4 + (ln >> 4)) * 2048 + N0 + (ln & 15) * 8;
    load_lds_16(g, (uint16_t*)pres[0] + wv * 512);
  }

  for (int t = 0; t < 256; ++t) {
    // 1. wait for h_{t-1} from my batch group (poison 0xAA.. is negative -> spins)
    if (t > 0 && ln < 16) {
      int v;
      do {
        v = __hip_atomic_load(&flags[bg * 16 + ln], __ATOMIC_RELAXED, __HIP_MEMORY_SCOPE_AGENT);
      } while (v < t);
    }

    // 2. stage h_{t-1} into Ahs (wave wv: rows wv*4..+4) + prefetch pre[t+1]
    if (t == 0) {
#pragma unroll
      for (int j = 0; j < 4; ++j) {
        int r = wv * 4 + j;
        *(uint4*)(Ahs + r * 544 + ln * 8) = make_uint4(0, 0, 0, 0);
      }
    } else {
      const uint16_t* hsrc = hbufs + (size_t)(t - 1) * 32768 + (size_t)bg * 16 * 512;
#pragma unroll
      for (int j = 0; j < 4; ++j) {
        int r = wv * 4 + j;
        load_lds_16(hsrc + r * 512 + ln * 8, Ahs + r * 544);
      }
    }
    {
      int tn = (t < 255) ? t + 1 : 255;
      const uint16_t* g = pre + (size_t)(tn * 64 + bg * 16 + wv * 4 + (ln >> 4)) * 2048 + N0 + (ln & 15) * 8;
      load_lds_16(g, (uint16_t*)pres[(t + 1) & 1] + wv * 512);
    }
    __syncthreads();

    // 3. MFMA: [16 x 512] x [512 x 32] per wave
    floatx4 acc[2] = {};
#pragma unroll
    for (int kc = 0; kc < 16; ++kc) {
      bf16x8 a = *(const bf16x8*)(Ahs + l16 * 544 + kc * 32 + q * 8);
#pragma unroll
      for (int nt = 0; nt < 2; ++nt)
        acc[nt] = __builtin_amdgcn_mfma_f32_16x16x32_bf16(a, Bfrag[kc][nt], acc[nt], 0, 0, 0);
    }

    // 4. gates = acc + bias + pre
    const uint16_t* pcur = (const uint16_t*)pres[t & 1];
#pragma unroll
    for (int nt = 0; nt < 2; ++nt) {
      int n_l = wv * 32 + nt * 16 + l16;
#pragma unroll
      for (int r = 0; r < 4; ++r) {
        int row = q * 4 + r;
        gates[row * 128 + n_l] = acc[nt][r] + breg[nt] + bf2f(pcur[row * 128 + n_l]);
      }
    }
    __syncthreads();

    // 5. epilogue: thread handles (b_l, h_l) and (b_l, h_l+1)
    {
      uint16_t* hdst = hbufs + (size_t)t * 32768;
      int item = tid * 2;
      int b_l = item >> 5, h_l = item & 31;    // h_l even
      float4 v0 = *(const float4*)(gates + b_l * 128 + h_l * 4);
      float4 v1 = *(const float4*)(gates + b_l * 128 + h_l * 4 + 4);
      float f0 = sigm(v0.x), i0 = sigm(v0.y), g0 = tanh_s(v0.z), o0 = sigm(v0.w);
      float f1 = sigm(v1.x), i1 = sigm(v1.y), g1 = tanh_s(v1.z), o1 = sigm(v1.w);
      float c0 = f0 * creg[0] + i0 * g0; creg[0] = c0;
      float c1 = f1 * creg[1] + i1 * g1; creg[1] = c1;
      float h0 = o0 * tanh_s(c0), h1 = o1 * tanh_s(c1);
      uint32_t pk = (uint32_t)f2bf(h0) | ((uint32_t)f2bf(h1) << 16);
      size_t idx = (size_t)(bg * 16 + b_l) * 512 + (size_t)cg * 32 + h_l;
      __hip_atomic_store((uint32_t*)(hdst + idx), pk, __ATOMIC_RELAXED, __HIP_MEMORY_SCOPE_AGENT);
      if (t == 255) {
        hfin[idx] = h0; hfin[idx + 1] = h1;
        cfin[idx] = c0; cfin[idx + 1] = c1;
      }
    }
    __syncthreads();  // drains vmcnt(0): all h stores at coherence point
    if (tid == 0)
      __hip_atomic_store(&flags[bg * 16 + cg], t + 1, __ATOMIC_RELAXED, __HIP_MEMORY_SCOPE_AGENT);
  }
}

// ---------- 6. final: out = h @ W_lin + b_lin; copy h, c ----------
__global__ __launch_bounds__(256) void k_final(const float* __restrict__ h, const float* __restrict__ c,
                                               const float* __restrict__ wl, const float* __restrict__ bl,
                                               float* __restrict__ out) {
  __shared__ float red[256];
  int b = blockIdx.x, t = threadIdx.x;
  const float* hb = h + (size_t)b * 512;
  if (t < 128) {
    ((float4*)(out + 320 + (size_t)b * 512))[t] = ((const float4*)hb)[t];
    ((float4*)(out + 320 + 32768 + (size_t)b * 512))[t] = ((const float4*)(c + (size_t)b * 512))[t];
  }
  float h0 = hb[t], h1 = hb[t + 256];
  for (int o = 0; o < 5; ++o) {
    red[t] = h0 * wl[t * 5 + o] + h1 * wl[(t + 256) * 5 + o];
    __syncthreads();
    for (int s = 128; s > 0; s >>= 1) {
      if (t < s) red[t] += red[t + s];
      __syncthreads();
    }
    if (t == 0) out[b * 5 + o] = red[0] + bl[o];
    __syncthreads();
  }
}

// ---------- launch ----------
extern "C" void kernel_launch(void* const* d_in, const int* in_sizes, int n_in,
                              void* d_out, int out_size, void* d_ws, size_t ws_size,
                              hipStream_t stream) {
  const int*   x   = (const int*)d_in[0];
  const float* emb = (const float*)d_in[1];
  const float* wfx = (const float*)d_in[2];
  const float* wfh = (const float*)d_in[3];
  const float* bf_ = (const float*)d_in[4];
  const float* wix = (const float*)d_in[5];
  const float* wih = (const float*)d_in[6];
  const float* bi_ = (const float*)d_in[7];
  const float* wgx = (const float*)d_in[8];
  const float* wgh = (const float*)d_in[9];
  const float* bg_ = (const float*)d_in[10];
  const float* wox = (const float*)d_in[11];
  const float* woh = (const float*)d_in[12];
  const float* bo_ = (const float*)d_in[13];
  const float* wl  = (const float*)d_in[14];
  const float* bl  = (const float*)d_in[15];
  float* out = (float*)d_out;
  char* ws = (char*)d_ws;

  uint16_t* embbf = (uint16_t*)(ws + OFF_EMB);
  uint16_t* hbufs = (uint16_t*)(ws + OFF_HBUF);
  uint16_t* wxt   = (uint16_t*)(ws + OFF_WXT);
  uint16_t* wht   = (uint16_t*)(ws + OFF_WHT);
  float*    bias  = (float*)(ws + OFF_BIAS);
  uint16_t* pre   = (uint16_t*)(ws + OFF_PRE);
  int*      flags = (int*)(ws + OFF_FLAGS);
  float*    hfin  = (float*)(ws + OFF_HF);
  float*    cfin  = (float*)(ws + OFF_CF);

  hipLaunchKernelGGL(k_emb_cvt, dim3(6250), dim3(256), 0, stream, emb, embbf);
  hipLaunchKernelGGL(k_wt, dim3(64, 32), dim3(256), 0, stream, wfx, wix, wgx, wox, 4096, wxt);
  hipLaunchKernelGGL(k_wt, dim3(8, 32), dim3(256), 0, stream, wfh, wih, wgh, woh, 512, wht);
  hipLaunchKernelGGL(k_bias, dim3(8), dim3(256), 0, stream, bf_, bi_, bg_, bo_, bias);
  hipLaunchKernelGGL(k_gemm, dim3(128, 16), dim3(256), 0, stream, embbf, x, wxt, pre);
  hipLaunchKernelGGL(k_rec, dim3(64), dim3(256), 0, stream, pre, wht, bias, hbufs, flags, hfin, cfin);
  hipLaunchKernelGGL(k_final, dim3(64), dim3(256), 0, stream, hfin, cfin, wl, bl, out);
}

// Round 3
// 1141.774 us; speedup vs baseline: 1.9640x; 1.0332x over previous
//
#include <hip/hip_runtime.h>
#include <stdint.h>

#define DEVI __device__ __forceinline__
typedef unsigned long long ull;

typedef __bf16 bf16x8 __attribute__((ext_vector_type(8)));
typedef float floatx4 __attribute__((ext_vector_type(4)));

// ---------- helpers ----------
DEVI uint16_t f2bf(float f) {
  union { float f; uint32_t u; } c; c.f = f;
  uint32_t u = c.u;
  return (uint16_t)((u + 0x7fffu + ((u >> 16) & 1u)) >> 16);  // RNE
}
DEVI float bf2f(uint16_t h) {
  union { uint32_t u; float f; } c; c.u = ((uint32_t)h) << 16;
  return c.f;
}
DEVI void load_lds_16(const void* g, void* l) {
  __builtin_amdgcn_global_load_lds(
      (const __attribute__((address_space(1))) void*)g,
      (__attribute__((address_space(3))) void*)l, 16, 0, 0);
}
DEVI float sigm(float x) { return 1.f / (1.f + __expf(-x)); }
DEVI float tanh_s(float x) {
  float xc = fminf(fmaxf(x, -15.f), 15.f);
  float e = __expf(2.f * xc);
  return (e - 1.f) / (e + 1.f);
}

// ---------- workspace layout (bytes) ----------
// emb_bf [50000][256] bf16 at 0 (dead after k_gemm; first 512KB reused as
// tagged-h scratch slabs for t=0,1).
// pre [256][64][2048] bf16; slab(t>=2) for tagged h aliases pre[t-2]:
//   per-bg slice at bg*65536 (first 32KB of the bg's own 64KB pre rows),
//   row stride 2048B, pair = 8B (payload bf16x2 | tag<<32).
static constexpr size_t OFF_EMB   = 0;
static constexpr size_t OFF_TS01  = 0;                        // 2*262144 scratch slabs
static constexpr size_t OFF_WXT   = 25600000;                 // [2048][4096] bf16
static constexpr size_t OFF_WHT   = OFF_WXT + 16777216;       // [2048][512] bf16
static constexpr size_t OFF_BIAS  = OFF_WHT + 2097152;        // [2048] f32
static constexpr size_t OFF_PRE   = OFF_BIAS + 8192;          // [256][64][2048] bf16
static constexpr size_t OFF_HF    = OFF_PRE + 67108864 + 4096;
static constexpr size_t OFF_CF    = OFF_HF + 131072;

// ---------- 1. embedding -> bf16, row 0 zeroed ----------
__global__ __launch_bounds__(256) void k_emb_cvt(const float* __restrict__ emb,
                                                 uint16_t* __restrict__ dst) {
  size_t tid = (size_t)blockIdx.x * 256 + threadIdx.x;
  size_t e = tid * 8;
  int v = (int)(e >> 8);
  const float4* s = (const float4*)(emb + e);
  float4 f0 = s[0], f1 = s[1];
  if (v == 0) { f0 = make_float4(0.f, 0.f, 0.f, 0.f); f1 = f0; }
  uint32_t w0 = f2bf(f0.x) | ((uint32_t)f2bf(f0.y) << 16);
  uint32_t w1 = f2bf(f0.z) | ((uint32_t)f2bf(f0.w) << 16);
  uint32_t w2 = f2bf(f1.x) | ((uint32_t)f2bf(f1.y) << 16);
  uint32_t w3 = f2bf(f1.z) | ((uint32_t)f2bf(f1.w) << 16);
  *(uint4*)(dst + e) = make_uint4(w0, w1, w2, w3);
}

// ---------- 2. weight transpose+convert: W_g[K][512] -> dst[n=h*4+g][K] bf16 ----------
__global__ __launch_bounds__(256) void k_wt(const float* __restrict__ w0, const float* __restrict__ w1,
                                            const float* __restrict__ w2, const float* __restrict__ w3,
                                            int K, uint16_t* __restrict__ dst) {
  __shared__ float tile[64 * 64];
  int k0 = blockIdx.x * 64;
  int n0 = blockIdx.y * 64;
  int h0 = blockIdx.y * 16;
  int g = threadIdx.x >> 6, di = threadIdx.x & 63;
  const float* w = (g == 0) ? w0 : (g == 1) ? w1 : (g == 2) ? w2 : w3;
  const float4* src = (const float4*)(w + (size_t)(k0 + di) * 512 + h0);
  float4 a = src[0], b = src[1], c = src[2], d = src[3];
  float vals[16] = {a.x, a.y, a.z, a.w, b.x, b.y, b.z, b.w,
                    c.x, c.y, c.z, c.w, d.x, d.y, d.z, d.w};
#pragma unroll
  for (int dh = 0; dh < 16; ++dh) tile[(dh * 4 + g) * 64 + di] = vals[dh];
  __syncthreads();
  int nl = threadIdx.x >> 2, ch = threadIdx.x & 3;
  uint32_t wb[8];
#pragma unroll
  for (int j = 0; j < 8; ++j) {
    float lo = tile[nl * 64 + ch * 16 + j * 2];
    float hi = tile[nl * 64 + ch * 16 + j * 2 + 1];
    wb[j] = f2bf(lo) | ((uint32_t)f2bf(hi) << 16);
  }
  uint4* dp = (uint4*)(dst + (size_t)(n0 + nl) * K + k0 + ch * 16);
  dp[0] = make_uint4(wb[0], wb[1], wb[2], wb[3]);
  dp[1] = make_uint4(wb[4], wb[5], wb[6], wb[7]);
}

// ---------- 3. bias pack ----------
__global__ __launch_bounds__(256) void k_bias(const float* __restrict__ b0, const float* __restrict__ b1,
                                              const float* __restrict__ b2, const float* __restrict__ b3,
                                              float* __restrict__ dst) {
  int n = blockIdx.x * 256 + threadIdx.x;
  int h = n >> 2, g = n & 3;
  const float* b = (g == 0) ? b0 : (g == 1) ? b1 : (g == 2) ? b2 : b3;
  dst[n] = b[h];
}

// ---------- 4. gather-GEMM (unchanged, known-good) ----------
__global__ __launch_bounds__(256) void k_gemm(const uint16_t* __restrict__ embbf,
                                              const int* __restrict__ x,
                                              const uint16_t* __restrict__ wxt,
                                              uint16_t* __restrict__ pre) {
  __shared__ uint16_t As[128 * 64];
  __shared__ uint16_t Bs[128 * 64];
  const int tid = threadIdx.x;
  const int wv = tid >> 6, ln = tid & 63;
  const int wm = wv >> 1, wn = wv & 1;
  const int M0 = blockIdx.x * 128, N0 = blockIdx.y * 128;
  const int srow = ln >> 3, schunk = ln & 7;

  const int* xrow[4];
  const uint16_t* bbase[4];
  uint16_t* ldsA[4];
  uint16_t* ldsB[4];
#pragma unroll
  for (int j = 0; j < 4; ++j) {
    int r = j * 32 + wv * 8 + srow;
    int m = M0 + r;
    int t = m >> 6, b = m & 63;
    xrow[j] = x + b * 4096 + t;
    bbase[j] = wxt + (size_t)(N0 + r) * 4096 + schunk * 8;
    ldsA[j] = As + (j * 32 + wv * 8) * 64;
    ldsB[j] = Bs + (j * 32 + wv * 8) * 64;
  }

  const int q = ln >> 4, l16 = ln & 15;
  int aoff[4], boff[4];
#pragma unroll
  for (int mt = 0; mt < 4; ++mt) aoff[mt] = (wm * 64 + mt * 16 + l16) * 64 + q * 8;
#pragma unroll
  for (int nt = 0; nt < 4; ++nt) boff[nt] = (wn * 64 + nt * 16 + l16) * 64 + q * 8;

  floatx4 acc[4][4] = {};

  for (int p = 0; p < 16; ++p) {
    const uint16_t* abase[4];
#pragma unroll
    for (int j = 0; j < 4; ++j) {
      int idx = xrow[j][p << 8];
      abase[j] = embbf + (size_t)idx * 256 + schunk * 8;
    }
#pragma unroll 1
    for (int ki = 0; ki < 4; ++ki) {
      __syncthreads();
#pragma unroll
      for (int j = 0; j < 4; ++j) load_lds_16(abase[j] + ki * 64, ldsA[j]);
#pragma unroll
      for (int j = 0; j < 4; ++j) load_lds_16(bbase[j] + p * 256 + ki * 64, ldsB[j]);
      __syncthreads();
#pragma unroll
      for (int kk = 0; kk < 2; ++kk) {
        bf16x8 a[4];
#pragma unroll
        for (int mt = 0; mt < 4; ++mt) a[mt] = *(const bf16x8*)(As + aoff[mt] + kk * 32);
#pragma unroll
        for (int nt = 0; nt < 4; ++nt) {
          bf16x8 bv = *(const bf16x8*)(Bs + boff[nt] + kk * 32);
#pragma unroll
          for (int mt = 0; mt < 4; ++mt)
            acc[mt][nt] = __builtin_amdgcn_mfma_f32_16x16x32_bf16(a[mt], bv, acc[mt][nt], 0, 0, 0);
        }
      }
    }
  }

#pragma unroll
  for (int mt = 0; mt < 4; ++mt) {
    int mg = M0 + wm * 64 + mt * 16 + q * 4;
#pragma unroll
    for (int nt = 0; nt < 4; ++nt) {
      int ng = N0 + wn * 64 + nt * 16 + l16;
#pragma unroll
      for (int r = 0; r < 4; ++r)
        pre[(size_t)(mg + r) * 2048 + ng] = f2bf(acc[mt][nt][r]);
    }
  }
}

// ---------- 5. persistent recurrence, tagged single-RT h exchange ----------
// 64 WGs = 4 bg x 16 cg. Wave wv owns gate-cols [N0+wv*32, +32) end-to-end
// (Bfrag, gates, epilogue) -> gates exchange is wave-local, ONE barrier/step.
// h_t passed as 8B atomic (bf16x2 payload | tag) words in dead pre[t-2] slabs.
__global__ __launch_bounds__(256) void k_rec(const uint16_t* pre,  // aliased by slabs - no restrict
                                             char* preb,
                                             char* scratch,
                                             const uint16_t* __restrict__ wht,
                                             const float* __restrict__ bias,
                                             float* __restrict__ hfin,
                                             float* __restrict__ cfin) {
  __shared__ uint16_t Ahs[2][16 * 544];     // h tile double buffer, row stride 544
  __shared__ uint16_t pres[2][16 * 128];    // pre strip double buffer
  __shared__ float gates[16 * 132];         // padded stride 132

  const int tid = threadIdx.x;
  const int wv = tid >> 6, ln = tid & 63;
  const int q = ln >> 4, l16 = ln & 15;
  const int bg = blockIdx.x >> 4, cg = blockIdx.x & 15;
  const int N0 = cg * 128;

  // B fragments resident in (A)GPRs: wave wv owns n-cols N0 + wv*32 .. +32
  bf16x8 Bfrag[16][2];
#pragma unroll
  for (int kc = 0; kc < 16; ++kc)
#pragma unroll
    for (int nt = 0; nt < 2; ++nt) {
      int n = N0 + wv * 32 + nt * 16 + l16;
      Bfrag[kc][nt] = *(const bf16x8*)(wht + (size_t)n * 512 + kc * 32 + q * 8);
    }
  float breg[2];
#pragma unroll
  for (int nt = 0; nt < 2; ++nt) breg[nt] = bias[N0 + wv * 32 + nt * 16 + l16];

  // poll/staging mapping: lane covers row prow, pairs pj+16*j (j=0..15)
  const int prow = wv * 4 + (ln >> 4);
  const int pj = ln & 15;
  // epilogue mapping: lane covers (erow, h cols wv*8 + es*2 .. +2) local to cg
  const int erow = ln >> 2;
  const int es = ln & 3;
  float creg[2] = {0.f, 0.f};

  // zero Ahs[0] (t=0 state h=0)
  for (int i = tid; i < 4352; i += 256) ((uint32_t*)Ahs[0])[i] = 0;
  // prefetch pre strip for t=0
  {
    const uint16_t* g = pre + (size_t)(bg * 16 + wv * 4 + (ln >> 4)) * 2048 + N0 + (ln & 15) * 8;
    load_lds_16(g, (uint16_t*)pres[0] + wv * 512);
  }

  for (int t = 0; t < 256; ++t) {
    if (t > 0) {
      // single-RT poll: tags + payload in one batch of 8B atomic loads
      const char* sb = (t - 1 < 2) ? scratch + (size_t)(t - 1) * 262144
                                   : preb + (size_t)(t - 3) * 262144;
      const ull* pp = (const ull*)(sb + (size_t)bg * 65536 + prow * 2048 + pj * 8);
      const uint32_t want = (uint32_t)t;
      ull v[16];
      bool ok = false;
      while (!ok) {
        ok = true;
#pragma unroll
        for (int j = 0; j < 16; ++j)
          v[j] = __hip_atomic_load(pp + j * 16, __ATOMIC_RELAXED, __HIP_MEMORY_SCOPE_AGENT);
#pragma unroll
        for (int j = 0; j < 16; ++j)
          ok = ok && ((uint32_t)(v[j] >> 32) == want);
        if (!ok) __builtin_amdgcn_s_sleep(1);
      }
      // stage payloads into Ahs[t&1] (2-way LDS bank pattern - free)
      uint16_t* dr = Ahs[t & 1] + prow * 544;
#pragma unroll
      for (int j = 0; j < 16; ++j)
        *(uint32_t*)(dr + 2 * pj + 32 * j) = (uint32_t)v[j];
    }
    __syncthreads();  // the ONE barrier per step (also drains pres prefetch)

    // MFMA [16 x 512] x [512 x 32] per wave, split into 2 chains of 8
    const uint16_t* Ab = Ahs[t & 1];
    floatx4 a0[2] = {}, a1[2] = {};
#pragma unroll
    for (int kc = 0; kc < 8; ++kc) {
      bf16x8 a = *(const bf16x8*)(Ab + l16 * 544 + kc * 32 + q * 8);
#pragma unroll
      for (int nt = 0; nt < 2; ++nt)
        a0[nt] = __builtin_amdgcn_mfma_f32_16x16x32_bf16(a, Bfrag[kc][nt], a0[nt], 0, 0, 0);
    }
#pragma unroll
    for (int kc = 8; kc < 16; ++kc) {
      bf16x8 a = *(const bf16x8*)(Ab + l16 * 544 + kc * 32 + q * 8);
#pragma unroll
      for (int nt = 0; nt < 2; ++nt)
        a1[nt] = __builtin_amdgcn_mfma_f32_16x16x32_bf16(a, Bfrag[kc][nt], a1[nt], 0, 0, 0);
    }

    // gates = acc + bias + pre (wave-local columns)
    const uint16_t* pcur = (const uint16_t*)pres[t & 1];
#pragma unroll
    for (int nt = 0; nt < 2; ++nt) {
      int n_l = wv * 32 + nt * 16 + l16;
      floatx4 s = a0[nt] + a1[nt];
#pragma unroll
      for (int r = 0; r < 4; ++r) {
        int row = q * 4 + r;
        gates[row * 132 + n_l] = s[r] + breg[nt] + bf2f(pcur[row * 128 + n_l]);
      }
    }
    // wave-local LDS exchange: compiler inserts lgkmcnt wait, no barrier needed

    // epilogue: 2 h-units per lane, tag-store 8B (payload|tag)
    {
      float4 v0 = *(const float4*)(gates + erow * 132 + wv * 32 + es * 8);
      float4 v1 = *(const float4*)(gates + erow * 132 + wv * 32 + es * 8 + 4);
      float f0 = sigm(v0.x), i0 = sigm(v0.y), g0 = tanh_s(v0.z), o0 = sigm(v0.w);
      float f1 = sigm(v1.x), i1 = sigm(v1.y), g1 = tanh_s(v1.z), o1 = sigm(v1.w);
      float c0 = f0 * creg[0] + i0 * g0; creg[0] = c0;
      float c1 = f1 * creg[1] + i1 * g1; creg[1] = c1;
      float h0 = o0 * tanh_s(c0), h1 = o1 * tanh_s(c1);
      char* sbw = (t < 2) ? scratch + (size_t)t * 262144
                          : preb + (size_t)(t - 2) * 262144;
      int pair = cg * 16 + wv * 4 + es;
      ull pk = (ull)((uint32_t)f2bf(h0) | ((uint32_t)f2bf(h1) << 16)) |
               ((ull)(uint32_t)(t + 1) << 32);
      __hip_atomic_store((ull*)(sbw + (size_t)bg * 65536 + erow * 2048 + pair * 8),
                         pk, __ATOMIC_RELAXED, __HIP_MEMORY_SCOPE_AGENT);
      if (t == 255) {
        size_t idx = (size_t)(bg * 16 + erow) * 512 + cg * 32 + wv * 8 + es * 2;
        hfin[idx] = h0; hfin[idx + 1] = h1;
        cfin[idx] = c0; cfin[idx + 1] = c1;
      }
    }

    // prefetch pre strip for t+1 (hidden under next poll window)
    {
      int tn = (t < 255) ? t + 1 : 255;
      const uint16_t* g = pre + (size_t)(tn * 64 + bg * 16 + wv * 4 + (ln >> 4)) * 2048 + N0 + (ln & 15) * 8;
      load_lds_16(g, (uint16_t*)pres[(t + 1) & 1] + wv * 512);
    }
  }
}

// ---------- 6. final: out = h @ W_lin + b_lin; copy h, c ----------
__global__ __launch_bounds__(256) void k_final(const float* __restrict__ h, const float* __restrict__ c,
                                               const float* __restrict__ wl, const float* __restrict__ bl,
                                               float* __restrict__ out) {
  __shared__ float red[256];
  int b = blockIdx.x, t = threadIdx.x;
  const float* hb = h + (size_t)b * 512;
  if (t < 128) {
    ((float4*)(out + 320 + (size_t)b * 512))[t] = ((const float4*)hb)[t];
    ((float4*)(out + 320 + 32768 + (size_t)b * 512))[t] = ((const float4*)(c + (size_t)b * 512))[t];
  }
  float h0 = hb[t], h1 = hb[t + 256];
  for (int o = 0; o < 5; ++o) {
    red[t] = h0 * wl[t * 5 + o] + h1 * wl[(t + 256) * 5 + o];
    __syncthreads();
    for (int s = 128; s > 0; s >>= 1) {
      if (t < s) red[t] += red[t + s];
      __syncthreads();
    }
    if (t == 0) out[b * 5 + o] = red[0] + bl[o];
    __syncthreads();
  }
}

// ---------- launch ----------
extern "C" void kernel_launch(void* const* d_in, const int* in_sizes, int n_in,
                              void* d_out, int out_size, void* d_ws, size_t ws_size,
                              hipStream_t stream) {
  const int*   x   = (const int*)d_in[0];
  const float* emb = (const float*)d_in[1];
  const float* wfx = (const float*)d_in[2];
  const float* wfh = (const float*)d_in[3];
  const float* bf_ = (const float*)d_in[4];
  const float* wix = (const float*)d_in[5];
  const float* wih = (const float*)d_in[6];
  const float* bi_ = (const float*)d_in[7];
  const float* wgx = (const float*)d_in[8];
  const float* wgh = (const float*)d_in[9];
  const float* bg_ = (const float*)d_in[10];
  const float* wox = (const float*)d_in[11];
  const float* woh = (const float*)d_in[12];
  const float* bo_ = (const float*)d_in[13];
  const float* wl  = (const float*)d_in[14];
  const float* bl  = (const float*)d_in[15];
  float* out = (float*)d_out;
  char* ws = (char*)d_ws;

  uint16_t* embbf = (uint16_t*)(ws + OFF_EMB);
  uint16_t* wxt   = (uint16_t*)(ws + OFF_WXT);
  uint16_t* wht   = (uint16_t*)(ws + OFF_WHT);
  float*    bias  = (float*)(ws + OFF_BIAS);
  uint16_t* pre   = (uint16_t*)(ws + OFF_PRE);
  float*    hfin  = (float*)(ws + OFF_HF);
  float*    cfin  = (float*)(ws + OFF_CF);

  hipLaunchKernelGGL(k_emb_cvt, dim3(6250), dim3(256), 0, stream, emb, embbf);
  hipLaunchKernelGGL(k_wt, dim3(64, 32), dim3(256), 0, stream, wfx, wix, wgx, wox, 4096, wxt);
  hipLaunchKernelGGL(k_wt, dim3(8, 32), dim3(256), 0, stream, wfh, wih, wgh, woh, 512, wht);
  hipLaunchKernelGGL(k_bias, dim3(8), dim3(256), 0, stream, bf_, bi_, bg_, bo_, bias);
  hipLaunchKernelGGL(k_gemm, dim3(128, 16), dim3(256), 0, stream, embbf, x, wxt, pre);
  hipLaunchKernelGGL(k_rec, dim3(64), dim3(256), 0, stream, pre, (char*)(ws + OFF_PRE),
                     ws + OFF_TS01, wht, bias, hfin, cfin);
  hipLaunchKernelGGL(k_final, dim3(64), dim3(256), 0, stream, hfin, cfin, wl, bl, out);
}